// Round 1
// baseline (3426.810 us; speedup 1.0000x reference)
//
#include <hip/hip_runtime.h>
#include <cstdint>
#include <cstddef>

// Problem constants
#define BB_ 16
#define HH_ 64
#define WW_ 64
#define CC_ 256
#define WD_ 127
#define RPD 1024   // rows per direction (B*H)
#define RT_ 2048   // total rows (both directions stacked)
#define NBLK 256   // cooperative grid size

typedef float  f32x4 __attribute__((ext_vector_type(4)));
typedef short  s16x8 __attribute__((ext_vector_type(8)));

__device__ __forceinline__ unsigned short f2bf(float f) {
  unsigned u = __float_as_uint(f);
  u += 0x7fffu + ((u >> 16) & 1u);   // round-to-nearest-even
  return (unsigned short)(u >> 16);
}
__device__ __forceinline__ float bf2f(unsigned short h) {
  return __uint_as_float(((unsigned)h) << 16);
}

// ---------------------------------------------------------------------------
// prep: masked i2s weights (fp32), W2T bf16 (gate-interleaved: n = chb*64 +
// g*16 + cl, original row j = g*256 + chb*16 + cl), fused biases, bar=0.
// ---------------------------------------------------------------------------
__global__ __launch_bounds__(256) void prep_kernel(
    const float* __restrict__ w_i2s, const float* __restrict__ b_i2s,
    const float* __restrict__ w_ih,  const float* __restrict__ b_ih,
    const float* __restrict__ b_hh,  const float* __restrict__ b_s2s,
    float* __restrict__ wm, unsigned short* __restrict__ W2T,
    float* __restrict__ cvec, float* __restrict__ gbias,
    unsigned* __restrict__ bar) {
  int idx = blockIdx.x * 256 + threadIdx.x;
  if (idx < 65536) {                       // wm[c][cin], masked
    int c = idx >> 8, ci = idx & 255;
    wm[idx] = ((ci % 3) <= (c % 3)) ? w_i2s[idx] : 0.0f;
  }
  int i3 = idx - 65536;                    // W2T[n][k] = w_ih[j(n)][k]
  if (i3 >= 0 && i3 < 262144) {
    int n = i3 >> 8, k = i3 & 255;
    int chb = n >> 6, g = (n >> 4) & 3, cl = n & 15;
    int j = g * 256 + chb * 16 + cl;
    W2T[i3] = f2bf(w_ih[j * 256 + k]);
  }
  int i4 = idx - 327680;                   // cvec = b_i2s + b_s2s
  if (i4 >= 0 && i4 < 256) cvec[i4] = b_i2s[i4] + b_s2s[i4];
  int i5 = idx - 327936;                   // gbias[n] = b_ih[j] + b_hh[j]
  if (i5 >= 0 && i5 < 1024) {
    int chb = i5 >> 6, g = (i5 >> 4) & 3, cl = i5 & 15;
    int j = g * 256 + chb * 16 + cl;
    gbias[i5] = b_ih[j] + b_hh[j];
  }
  if (idx == 328960) *bar = 0u;            // zero grid barrier each replay
}

// ---------------------------------------------------------------------------
// prep2: combined recurrent weights MM[n][k2] (bf16):
//   k2 <  256 : M0[n][c] = sum_k w_ih[j(n)][k] * k0[k][c]   (pairs h_prev)
//   k2 >= 256 : M1[n][c] = sum_k w_ih[j(n)][k] * k1[k][c]   (pairs h_next)
// and gbias2[n] = gbias[n] + sum_k w_ih[j(n)][k] * cvec[k].
// ---------------------------------------------------------------------------
__global__ __launch_bounds__(256) void prep2_kernel(
    const float* __restrict__ w_ih, const float* __restrict__ k0,
    const float* __restrict__ k1,   const float* __restrict__ cvec,
    const float* __restrict__ gbias, unsigned short* __restrict__ MM,
    float* __restrict__ gbias2) {
  __shared__ float wr[4][256];
  __shared__ float red[256];
  int bid = blockIdx.x, tid = threadIdx.x;
#pragma unroll
  for (int q = 0; q < 4; q++) {
    int n = bid * 4 + q;
    int chb = n >> 6, g = (n >> 4) & 3, cl = n & 15;
    int j = g * 256 + chb * 16 + cl;
    wr[q][tid] = w_ih[j * 256 + tid];
  }
  __syncthreads();
  int c = tid;
  float a0[4] = {0.f, 0.f, 0.f, 0.f}, a1[4] = {0.f, 0.f, 0.f, 0.f};
  for (int k = 0; k < 256; k++) {
    float v0 = k0[k * 256 + c], v1 = k1[k * 256 + c];
#pragma unroll
    for (int q = 0; q < 4; q++) {
      a0[q] = fmaf(wr[q][k], v0, a0[q]);
      a1[q] = fmaf(wr[q][k], v1, a1[q]);
    }
  }
#pragma unroll
  for (int q = 0; q < 4; q++) {
    int n = bid * 4 + q;
    MM[(size_t)n * 512 + c]       = f2bf(a0[q]);
    MM[(size_t)n * 512 + 256 + c] = f2bf(a1[q]);
  }
  float cv = cvec[c];
#pragma unroll
  for (int q = 0; q < 4; q++) {
    red[tid] = wr[q][tid] * cv;
    __syncthreads();
    for (int s = 128; s > 0; s >>= 1) {
      if (tid < s) red[tid] += red[tid + s];
      __syncthreads();
    }
    if (tid == 0) { int n = bid * 4 + q; gbias2[n] = gbias[n] + red[0]; }
    __syncthreads();
  }
}

// ---------------------------------------------------------------------------
// xs: banded masked 1x1 conv, computed once per (bb,i), reused for both
// directions. Output xs[dir][row][j][c] bf16 (c contiguous), j = t - i.
// ---------------------------------------------------------------------------
__global__ __launch_bounds__(256) void xs_kernel(
    const float* __restrict__ x, const float* __restrict__ wm,
    unsigned short* __restrict__ xs) {
  extern __shared__ float xt[];                   // [256 cin][64 j]
  int blk = blockIdx.x;                           // bb*64 + i
  int bb = blk >> 6, ii = blk & 63;
  int tid = threadIdx.x;
  {
    const float4* src = (const float4*)(x + (((size_t)bb * 256 + tid) * 64 + ii) * 64);
    float4* dst = (float4*)(xt + tid * 64);
#pragma unroll
    for (int q = 0; q < 16; q++) dst[q] = src[q];
  }
  __syncthreads();

  int cp = tid & 127, c0 = cp * 2;
  int j0 = (tid >> 7) * 32;                       // wave-uniform (0 or 32)
  float acc0[32], acc1[32];
#pragma unroll
  for (int q = 0; q < 32; q++) { acc0[q] = 0.f; acc1[q] = 0.f; }

  for (int c4 = 0; c4 < 64; c4++) {
    float4 wa = *(const float4*)(wm + c0 * 256 + c4 * 4);
    float4 wb = *(const float4*)(wm + (c0 + 1) * 256 + c4 * 4);
    float wav[4] = {wa.x, wa.y, wa.z, wa.w};
    float wbv[4] = {wb.x, wb.y, wb.z, wb.w};
#pragma unroll
    for (int j4 = 0; j4 < 8; j4++) {
#pragma unroll
      for (int i = 0; i < 4; i++) {
        float4 xv = *(const float4*)(xt + (c4 * 4 + i) * 64 + j0 + j4 * 4);
        acc0[j4 * 4 + 0] = fmaf(wav[i], xv.x, acc0[j4 * 4 + 0]);
        acc0[j4 * 4 + 1] = fmaf(wav[i], xv.y, acc0[j4 * 4 + 1]);
        acc0[j4 * 4 + 2] = fmaf(wav[i], xv.z, acc0[j4 * 4 + 2]);
        acc0[j4 * 4 + 3] = fmaf(wav[i], xv.w, acc0[j4 * 4 + 3]);
        acc1[j4 * 4 + 0] = fmaf(wbv[i], xv.x, acc1[j4 * 4 + 0]);
        acc1[j4 * 4 + 1] = fmaf(wbv[i], xv.y, acc1[j4 * 4 + 1]);
        acc1[j4 * 4 + 2] = fmaf(wbv[i], xv.z, acc1[j4 * 4 + 2]);
        acc1[j4 * 4 + 3] = fmaf(wbv[i], xv.w, acc1[j4 * 4 + 3]);
      }
    }
  }
  size_t row = (size_t)blk;
#pragma unroll
  for (int q = 0; q < 32; q++) {
    int j = j0 + q;
    unsigned pv = (unsigned)f2bf(acc0[q]) | ((unsigned)f2bf(acc1[q]) << 16);
    *(unsigned*)(xs + ((row * 64 + j) * 256 + c0)) = pv;                      // dir0
    *(unsigned*)(xs + (16777216u + (row * 64 + (63 - j)) * 256 + c0)) = pv;   // dir1
  }
}

// ---------------------------------------------------------------------------
// loop: persistent cooperative kernel. 256 blocks x 512 thr, 1 block/CU.
// Block = (slab s: 128 rows) x (chb v: 16 channels = 64 gate-cols).
// Per step: gates = h_prev @ [M0|M1]^T (bf16 MFMA, K=512, contiguous-row
// trick gives h_next at +256) + xs_t @ W2T^T (K=256, banded) + gbias2,
// then fused LSTM; cstate in VGPRs. One grid barrier per step.
// Weights in LDS with 16B XOR swizzle (bank-even for ds_read_b128).
// XCD mapping: same-slab blocks co-located (assumes XCD = bid&7).
// ---------------------------------------------------------------------------
__global__ __launch_bounds__(512, 2) void loop_kernel(
    const unsigned short* __restrict__ xs,
    const unsigned short* __restrict__ MM,
    const unsigned short* __restrict__ W2T,
    const float* __restrict__ gbias2,
    unsigned short* __restrict__ hs,
    unsigned* __restrict__ bar) {
  __shared__ unsigned short smm[32768];   // 64 KiB: MM slice [64][512] swz
  __shared__ unsigned short sw2[16384];   // 32 KiB: W2T slice [64][256] swz
  int bid = blockIdx.x;
  int s = (bid & 7) * 2 + ((bid >> 3) & 1);   // slab 0..15 (XCD-grouped)
  int v = bid >> 4;                            // chb 0..15
  int r0 = s * 128, n0 = v * 64;
  int tid = threadIdx.x, lane = tid & 63, w = tid >> 6;
  int l15 = lane & 15, l4 = lane >> 4;

  // stage weights -> LDS (16B-chunk XOR swizzle on bits 4-6 within row)
  for (int idx = tid; idx < 4096; idx += 512) {
    int nn = idx >> 6, kc = idx & 63;
    s16x8 val = *(const s16x8*)(MM + (size_t)(n0 + nn) * 512 + kc * 8);
    int dst = (nn << 10) + ((kc << 4) ^ ((nn & 7) << 4));
    *(s16x8*)((char*)smm + dst) = val;
  }
  for (int idx = tid; idx < 2048; idx += 512) {
    int nn = idx >> 5, kc = idx & 31;
    s16x8 val = *(const s16x8*)(W2T + (size_t)(n0 + nn) * 256 + kc * 8);
    int dst = (nn << 9) + ((kc << 4) ^ ((nn & 7) << 4));
    *(s16x8*)((char*)sw2 + dst) = val;
  }
  __syncthreads();

  int rbase = r0 + w * 16;                     // wave's 16 rows
  float gb[4];
#pragma unroll
  for (int ni = 0; ni < 4; ni++) gb[ni] = gbias2[n0 + ni * 16 + l15];
  int ch = v * 16 + l15;
  float cst[4] = {0.f, 0.f, 0.f, 0.f};

  int Rl = rbase + l15;                        // A-frag row for this lane
  int rl = Rl & 1023, dir = Rl >> 10, ii = rl & 63;
  bool lastrow = (rl == 1023);                 // h_next masked to zero
  const unsigned short* xrow = xs + (size_t)dir * 16777216u + (size_t)rl * 16384;
  int iimin = rbase & 63;                      // wave-uniform band window

  for (int t = 0; t < 127; ++t) {
    f32x4 acc[4];
#pragma unroll
    for (int ni = 0; ni < 4; ni++) acc[ni] = (f32x4){0.f, 0.f, 0.f, 0.f};
    const s16x8 zz = {0, 0, 0, 0, 0, 0, 0, 0};

    // ---- xs part: acc += xs_t @ W2T^T (skip when whole wave out-of-band)
    if (t >= iimin && t <= iimin + 78) {
      int j = t - ii;
      bool inband = (j >= 0) && (j < 64);
      const unsigned short* pax = xrow + (ptrdiff_t)j * 256;
#pragma unroll
      for (int ks = 0; ks < 8; ks++) {
        int kk = ks * 32 + l4 * 8;
        s16x8 a = inband ? *(const s16x8*)(pax + kk) : zz;
#pragma unroll
        for (int ni = 0; ni < 4; ni++) {
          int row = ni * 16 + l15;
          int off = (row << 9) + (((ks * 64) + (l4 << 4)) ^ ((row & 7) << 4));
          s16x8 b = *(const s16x8*)((const char*)sw2 + off);
          acc[ni] = __builtin_amdgcn_mfma_f32_16x16x32_bf16(a, b, acc[ni], 0, 0, 0);
        }
      }
    }
    // ---- recurrent part: acc += h_prev @ [M0|M1]^T  (k2>=256 reads row+1)
    if (t > 0) {
      const unsigned short* pah = hs + (size_t)(t - 1) * 524288 + (size_t)Rl * 256;
#pragma unroll
      for (int ks = 0; ks < 16; ks++) {
        int k2 = ks * 32 + l4 * 8;
        s16x8 a = (lastrow && ks >= 8) ? zz : *(const s16x8*)(pah + k2);
#pragma unroll
        for (int ni = 0; ni < 4; ni++) {
          int row = ni * 16 + l15;
          int off = (row << 10) + (((ks * 64) + (l4 << 4)) ^ ((row & 7) << 4));
          s16x8 b = *(const s16x8*)((const char*)smm + off);
          acc[ni] = __builtin_amdgcn_mfma_f32_16x16x32_bf16(a, b, acc[ni], 0, 0, 0);
        }
      }
    }
    // ---- fused LSTM epilogue (C/D: row = l4*4+r, col = l15)
    unsigned short* hout = hs + (size_t)t * 524288;
#pragma unroll
    for (int r = 0; r < 4; r++) {
      int R = rbase + l4 * 4 + r;
      float xi = acc[0][r] + gb[0];
      float xf = acc[1][r] + gb[1];
      float xg = acc[2][r] + gb[2];
      float xo = acc[3][r] + gb[3];
      float si = 1.f / (1.f + __expf(-xi));
      float sf = 1.f / (1.f + __expf(-xf));
      float so = 1.f / (1.f + __expf(-xo));
      float tg = 1.f - 2.f / (__expf(2.f * xg) + 1.f);
      float cn = sf * cst[r] + si * tg;
      cst[r] = cn;
      float th = 1.f - 2.f / (__expf(2.f * cn) + 1.f);
      hout[(size_t)R * 256 + ch] = f2bf(so * th);
    }
    // ---- grid barrier (monotone counter; release/acquire via threadfence)
    if (t < 126) {
      __syncthreads();
      if (tid == 0) {
        __threadfence();
        __hip_atomic_fetch_add(bar, 1u, __ATOMIC_RELAXED, __HIP_MEMORY_SCOPE_AGENT);
        unsigned tgt = (unsigned)(t + 1) * NBLK;
        while (__hip_atomic_load(bar, __ATOMIC_RELAXED, __HIP_MEMORY_SCOPE_AGENT) < tgt) {
          __builtin_amdgcn_s_sleep(4);
        }
        __threadfence();
      }
      __syncthreads();
    }
  }
}

// ---------------------------------------------------------------------------
// gather: out[b,o,hh,j] = hs0[hh+j][row][c0+hh] + (hh>0)*hs1[hh-1+63-j][row][c0+hh-1]
// ---------------------------------------------------------------------------
__global__ __launch_bounds__(256) void gather_kernel(
    const unsigned short* __restrict__ hs, float* __restrict__ out) {
  __shared__ unsigned short slab0[127 * 66 + 2];
  __shared__ unsigned short slab1[127 * 66 + 2];
  int blk = blockIdx.x;                    // bb*256 + o
  int bb = blk >> 8, o = blk & 255;
  int row = bb * 64 + (o >> 2);
  int c0 = (o & 3) * 64;
  int tid = threadIdx.x;
  for (int idx = tid; idx < 127 * 32; idx += 256) {
    int tt = idx >> 5, cu = idx & 31;
    unsigned v0 = *(const unsigned*)(hs + ((size_t)tt * RT_ + row) * 256 + c0 + cu * 2);
    unsigned v1 = *(const unsigned*)(hs + ((size_t)tt * RT_ + 1024 + row) * 256 + c0 + cu * 2);
    *(unsigned*)(slab0 + tt * 66 + cu * 2) = v0;
    *(unsigned*)(slab1 + tt * 66 + cu * 2) = v1;
  }
  __syncthreads();
  int j = tid & 63;
  int hh0 = (tid >> 6) * 16;
  float* ob = out + (size_t)blk * 4096;
  for (int hh = hh0; hh < hh0 + 16; hh++) {
    float v = bf2f(slab0[(hh + j) * 66 + hh]);
    if (hh > 0) v += bf2f(slab1[(hh - 1 + 63 - j) * 66 + (hh - 1)]);
    ob[hh * 64 + j] = v;
  }
}

// ---------------------------------------------------------------------------
extern "C" void kernel_launch(void* const* d_in, const int* in_sizes, int n_in,
                              void* d_out, int out_size, void* d_ws, size_t ws_size,
                              hipStream_t stream) {
  const float* x     = (const float*)d_in[0];
  const float* w_i2s = (const float*)d_in[1];
  const float* b_i2s = (const float*)d_in[2];
  const float* w_ih  = (const float*)d_in[3];
  const float* b_ih  = (const float*)d_in[4];
  const float* b_hh  = (const float*)d_in[5];
  const float* k0    = (const float*)d_in[6];
  const float* k1    = (const float*)d_in[7];
  const float* b_s2s = (const float*)d_in[8];
  float* out = (float*)d_out;

  char* ws = (char*)d_ws;
  // workspace map (bytes)
  float*          wm     = (float*)(ws + 0);                 //   256 KiB
  float*          cvec   = (float*)(ws + 262144);            //     1 KiB
  float*          gbias  = (float*)(ws + 263168);            //     4 KiB
  float*          gbias2 = (float*)(ws + 267264);            //     4 KiB
  unsigned*       bar    = (unsigned*)(ws + 271360);         //     4 B (pad 1K)
  unsigned short* W2T    = (unsigned short*)(ws + 272384);   //   512 KiB
  unsigned short* MM     = (unsigned short*)(ws + 796672);   //     1 MiB
  unsigned short* xs     = (unsigned short*)(ws + 1845248);  //    64 MiB
  unsigned short* hs     = (unsigned short*)(ws + 68954112); //   127 MiB
  const size_t NEEDED = 202123264;
  if (ws_size < NEEDED) return;  // workspace too small; fail loudly via mismatch

  prep_kernel<<<1286, 256, 0, stream>>>(w_i2s, b_i2s, w_ih, b_ih, b_hh, b_s2s,
                                        wm, W2T, cvec, gbias, bar);
  prep2_kernel<<<256, 256, 0, stream>>>(w_ih, k0, k1, cvec, gbias, MM, gbias2);
  xs_kernel<<<1024, 256, 65536, stream>>>(x, wm, xs);

  {
    const unsigned short* a0 = xs;
    const unsigned short* a1 = MM;
    const unsigned short* a2 = W2T;
    const float*          a3 = gbias2;
    unsigned short*       a4 = hs;
    unsigned*             a5 = bar;
    void* kargs[6] = {(void*)&a0, (void*)&a1, (void*)&a2,
                      (void*)&a3, (void*)&a4, (void*)&a5};
    hipLaunchCooperativeKernel((const void*)loop_kernel, dim3(NBLK), dim3(512),
                               kargs, 0, stream);
  }

  gather_kernel<<<4096, 256, 0, stream>>>(hs, out);
}

// Round 2
// 1761.659 us; speedup vs baseline: 1.9452x; 1.9452x over previous
//
#include <hip/hip_runtime.h>
#include <cstdint>
#include <cstddef>

// Problem constants
#define BB_ 16
#define HH_ 64
#define WW_ 64
#define CC_ 256
#define WD_ 127
#define RPD 1024   // rows per direction (B*H)
#define RT_ 2048   // total rows (both directions stacked)
#define NBLK 256   // persistent grid size

typedef float  f32x4 __attribute__((ext_vector_type(4)));
typedef short  s16x8 __attribute__((ext_vector_type(8)));
typedef int    i32x4 __attribute__((ext_vector_type(4)));

__device__ __forceinline__ unsigned short f2bf(float f) {
  unsigned u = __float_as_uint(f);
  u += 0x7fffu + ((u >> 16) & 1u);   // round-to-nearest-even
  return (unsigned short)(u >> 16);
}
__device__ __forceinline__ float bf2f(unsigned short h) {
  return __uint_as_float(((unsigned)h) << 16);
}

// ---------------------------------------------------------------------------
// prep: masked i2s weights (fp32), XP = xs-B-operand pack (fragment-major:
// XP[v][ks][ni][lane][8]), fused biases, slab counters -> 0.
// Gate-interleave: n = chb*64 + g*16 + cl, original row j = g*256 + chb*16+cl.
// ---------------------------------------------------------------------------
__global__ __launch_bounds__(256) void prep_kernel(
    const float* __restrict__ w_i2s, const float* __restrict__ b_i2s,
    const float* __restrict__ w_ih,  const float* __restrict__ b_ih,
    const float* __restrict__ b_hh,  const float* __restrict__ b_s2s,
    float* __restrict__ wm, unsigned short* __restrict__ XP,
    float* __restrict__ cvec, float* __restrict__ gbias,
    unsigned* __restrict__ cnt) {
  int idx = blockIdx.x * 256 + threadIdx.x;
  if (idx < 65536) {                       // wm[c][cin], masked
    int c = idx >> 8, ci = idx & 255;
    wm[idx] = ((ci % 3) <= (c % 3)) ? w_i2s[idx] : 0.0f;
  }
  int i3 = idx - 65536;                    // XP pack of w_ih
  if (i3 >= 0 && i3 < 262144) {
    int n = i3 >> 8, k = i3 & 255;
    int chb = n >> 6, g = (n >> 4) & 3, cl = n & 15;
    int j = g * 256 + chb * 16 + cl;
    float val = w_ih[j * 256 + k];
    int ks = k >> 5, l4k = (k >> 3) & 3, e = k & 7;
    size_t o = (size_t)chb * 16384 + (size_t)(ks * 4 + g) * 512 +
               (size_t)(l4k * 16 + cl) * 8 + e;
    XP[o] = f2bf(val);
  }
  int i4 = idx - 327680;                   // cvec = b_i2s + b_s2s
  if (i4 >= 0 && i4 < 256) cvec[i4] = b_i2s[i4] + b_s2s[i4];
  int i5 = idx - 327936;                   // gbias[n] = b_ih[j] + b_hh[j]
  if (i5 >= 0 && i5 < 1024) {
    int chb = i5 >> 6, g = (i5 >> 4) & 3, cl = i5 & 15;
    int j = g * 256 + chb * 16 + cl;
    gbias[i5] = b_ih[j] + b_hh[j];
  }
  int i6 = idx - 328960;                   // slab counters (64B apart)
  if (i6 >= 0 && i6 < 16) cnt[i6 * 16] = 0u;
}

// ---------------------------------------------------------------------------
// prep2: combined recurrent weights, packed fragment-major into RP:
//   k2 <  256 : M0[n][c] = sum_k w_ih[j(n)][k] * k0[k][c]   (pairs h_prev)
//   k2 >= 256 : M1[n][c] = sum_k w_ih[j(n)][k] * k1[k][c]   (pairs h_next)
// RP[v][ks(16)][ni(4)][lane(64)][8] bf16.  Also gbias2 = gbias + W2 @ cvec.
// ---------------------------------------------------------------------------
__global__ __launch_bounds__(256) void prep2_kernel(
    const float* __restrict__ w_ih, const float* __restrict__ k0,
    const float* __restrict__ k1,   const float* __restrict__ cvec,
    const float* __restrict__ gbias, unsigned short* __restrict__ RP,
    float* __restrict__ gbias2) {
  __shared__ float wr[4][256];
  __shared__ float red[256];
  int bid = blockIdx.x, tid = threadIdx.x;
#pragma unroll
  for (int q = 0; q < 4; q++) {
    int n = bid * 4 + q;
    int chb = n >> 6, g = (n >> 4) & 3, cl = n & 15;
    int j = g * 256 + chb * 16 + cl;
    wr[q][tid] = w_ih[j * 256 + tid];
  }
  __syncthreads();
  int c = tid;
  float a0[4] = {0.f, 0.f, 0.f, 0.f}, a1[4] = {0.f, 0.f, 0.f, 0.f};
  for (int k = 0; k < 256; k++) {
    float v0 = k0[k * 256 + c], v1 = k1[k * 256 + c];
#pragma unroll
    for (int q = 0; q < 4; q++) {
      a0[q] = fmaf(wr[q][k], v0, a0[q]);
      a1[q] = fmaf(wr[q][k], v1, a1[q]);
    }
  }
  int ks0 = c >> 5, l40 = (c >> 3) & 3, e0 = c & 7;
#pragma unroll
  for (int q = 0; q < 4; q++) {
    int n = bid * 4 + q;
    int vv = n >> 6, nii = (n >> 4) & 3, ll = n & 15;
    size_t i0 = (size_t)vv * 32768 + (size_t)(ks0 * 4 + nii) * 512 +
                (size_t)(l40 * 16 + ll) * 8 + e0;
    size_t i1 = (size_t)vv * 32768 + (size_t)((ks0 + 8) * 4 + nii) * 512 +
                (size_t)(l40 * 16 + ll) * 8 + e0;
    RP[i0] = f2bf(a0[q]);
    RP[i1] = f2bf(a1[q]);
  }
  float cv = cvec[c];
#pragma unroll
  for (int q = 0; q < 4; q++) {
    red[tid] = wr[q][tid] * cv;
    __syncthreads();
    for (int s = 128; s > 0; s >>= 1) {
      if (tid < s) red[tid] += red[tid + s];
      __syncthreads();
    }
    if (tid == 0) { int n = bid * 4 + q; gbias2[n] = gbias[n] + red[0]; }
    __syncthreads();
  }
}

// ---------------------------------------------------------------------------
// xs: banded masked 1x1 conv, computed once per (bb,i), reused for both
// directions. Output xs[dir][row][j][c] bf16 (c contiguous), j = t - i.
// ---------------------------------------------------------------------------
__global__ __launch_bounds__(256) void xs_kernel(
    const float* __restrict__ x, const float* __restrict__ wm,
    unsigned short* __restrict__ xs) {
  extern __shared__ float xt[];                   // [256 cin][64 j]
  int blk = blockIdx.x;                           // bb*64 + i
  int bb = blk >> 6, ii = blk & 63;
  int tid = threadIdx.x;
  {
    const float4* src = (const float4*)(x + (((size_t)bb * 256 + tid) * 64 + ii) * 64);
    float4* dst = (float4*)(xt + tid * 64);
#pragma unroll
    for (int q = 0; q < 16; q++) dst[q] = src[q];
  }
  __syncthreads();

  int cp = tid & 127, c0 = cp * 2;
  int j0 = (tid >> 7) * 32;                       // wave-uniform (0 or 32)
  float acc0[32], acc1[32];
#pragma unroll
  for (int q = 0; q < 32; q++) { acc0[q] = 0.f; acc1[q] = 0.f; }

  for (int c4 = 0; c4 < 64; c4++) {
    float4 wa = *(const float4*)(wm + c0 * 256 + c4 * 4);
    float4 wb = *(const float4*)(wm + (c0 + 1) * 256 + c4 * 4);
    float wav[4] = {wa.x, wa.y, wa.z, wa.w};
    float wbv[4] = {wb.x, wb.y, wb.z, wb.w};
#pragma unroll
    for (int j4 = 0; j4 < 8; j4++) {
#pragma unroll
      for (int i = 0; i < 4; i++) {
        float4 xv = *(const float4*)(xt + (c4 * 4 + i) * 64 + j0 + j4 * 4);
        acc0[j4 * 4 + 0] = fmaf(wav[i], xv.x, acc0[j4 * 4 + 0]);
        acc0[j4 * 4 + 1] = fmaf(wav[i], xv.y, acc0[j4 * 4 + 1]);
        acc0[j4 * 4 + 2] = fmaf(wav[i], xv.z, acc0[j4 * 4 + 2]);
        acc0[j4 * 4 + 3] = fmaf(wav[i], xv.w, acc0[j4 * 4 + 3]);
        acc1[j4 * 4 + 0] = fmaf(wbv[i], xv.x, acc1[j4 * 4 + 0]);
        acc1[j4 * 4 + 1] = fmaf(wbv[i], xv.y, acc1[j4 * 4 + 1]);
        acc1[j4 * 4 + 2] = fmaf(wbv[i], xv.z, acc1[j4 * 4 + 2]);
        acc1[j4 * 4 + 3] = fmaf(wbv[i], xv.w, acc1[j4 * 4 + 3]);
      }
    }
  }
  size_t row = (size_t)blk;
#pragma unroll
  for (int q = 0; q < 32; q++) {
    int j = j0 + q;
    unsigned pv = (unsigned)f2bf(acc0[q]) | ((unsigned)f2bf(acc1[q]) << 16);
    *(unsigned*)(xs + ((row * 64 + j) * 256 + c0)) = pv;                      // dir0
    *(unsigned*)(xs + (16777216u + (row * 64 + (63 - j)) * 256 + c0)) = pv;   // dir1
  }
}

// ---------------------------------------------------------------------------
// loop: persistent kernel, NO fences. 256 blocks x 512 thr (1/CU).
// Block = slab s (128 rows) x vgroup v (64 gate-cols). 8 waves =
// 4 rowgroups(32r) x 2 K-halves. h state flows through the LLC only:
// stores/loads use sc0 sc1 (device-coherent, bypass L1/L2); sync is a
// per-slab monotone counter (device atomics) + neighbor-slab check for the
// one halo row. Per step: stage h[t-1] slab -> LDS (XOR-swizzled) while
// computing the xs partial; rec partial from LDS A x L2-packed B; K-halves
// reduced via LDS; fused LSTM epilogue with cstate in registers.
// ---------------------------------------------------------------------------
__global__ __launch_bounds__(512, 2) void loop_kernel(
    const unsigned short* __restrict__ xs,
    const unsigned short* __restrict__ RP,
    const unsigned short* __restrict__ XP,
    const float* __restrict__ gbias2,
    unsigned short* __restrict__ hs,
    unsigned* __restrict__ cnt) {
  __shared__ __align__(16) unsigned short hsl[33024];  // 129 rows x 512B
  __shared__ __align__(16) float redbuf[9216];         // 4 rg x 64 col x 36

  int bid = blockIdx.x;
  int v = (bid & 7) * 2 + ((bid >> 3) & 1);   // vgroup (XCD-grouped: B reuse)
  int s = bid >> 4;                            // slab 0..15
  int r0 = s * 128, n0 = v * 64;
  int tid = threadIdx.x, lane = tid & 63, w = tid >> 6;
  int rg = w >> 1, kh = w & 1;
  int l15 = lane & 15, l4 = lane >> 4;
  int rbase = r0 + rg * 32;

  // biases + cstate (kh0 waves own the epilogue)
  float gb0 = gbias2[n0 + l15];
  float gb1 = gbias2[n0 + 16 + l15];
  float gb2 = gbias2[n0 + 32 + l15];
  float gb3 = gbias2[n0 + 48 + l15];
  int ch = v * 16 + l15;
  float cst[8];
#pragma unroll
  for (int q = 0; q < 8; q++) cst[q] = 0.f;

  // xs row bases (per mi)
  int Rl0 = rbase + l15, Rl1 = Rl0 + 16;
  const unsigned short* xb0 =
      xs + (size_t)(Rl0 >> 10) * 16777216u + (size_t)(Rl0 & 1023) * 16384;
  const unsigned short* xb1 =
      xs + (size_t)(Rl1 >> 10) * 16777216u + (size_t)(Rl1 & 1023) * 16384;
  int ii0 = (rg & 1) * 32 + l15, ii1 = ii0 + 16;
  int iimin = (rg & 1) * 32;
  bool m1 = ((s & 7) == 7) && (rg == 3) && (l15 == 15);  // last in-dir row
  int row0 = rg * 32 + l15;                               // block-local A row
  bool neednb = ((s & 7) != 7);
  unsigned* mycnt = cnt + s * 16;
  unsigned* nbcnt = cnt + (s + 1) * 16;
  const unsigned short* RPb = RP + (size_t)v * 32768 + (size_t)lane * 8;
  const unsigned short* XPb = XP + (size_t)v * 16384 + (size_t)lane * 8;
  const s16x8 zz = {0, 0, 0, 0, 0, 0, 0, 0};

  for (int t = 0; t < 127; ++t) {
    f32x4 acc[2][4];
#pragma unroll
    for (int mi = 0; mi < 2; mi++)
#pragma unroll
      for (int ni = 0; ni < 4; ni++) acc[mi][ni] = (f32x4){0.f, 0.f, 0.f, 0.f};

    i32x4 stg[8]; i32x4 stg8;
    if (t > 0) {
      // ---- per-slab sync: peers done t-1, neighbor slab done t-1 (halo)
      if (tid == 0) {
        unsigned tgt = (unsigned)t * 16u;
        while (__hip_atomic_load(mycnt, __ATOMIC_RELAXED,
                                 __HIP_MEMORY_SCOPE_AGENT) < tgt)
          __builtin_amdgcn_s_sleep(2);
        if (neednb) {
          while (__hip_atomic_load(nbcnt, __ATOMIC_RELAXED,
                                   __HIP_MEMORY_SCOPE_AGENT) < tgt)
            __builtin_amdgcn_s_sleep(2);
        }
      }
      __syncthreads();
      // ---- issue h[t-1] slab staging loads (129 rows, device-coherent)
      const unsigned short* src = hs + (size_t)(t - 1) * 524288 + (size_t)r0 * 256;
#pragma unroll
      for (int q = 0; q < 8; q++) {
        const unsigned short* p = src + (size_t)(tid + q * 512) * 8;
        asm volatile("global_load_dwordx4 %0, %1, off sc0 sc1"
                     : "=v"(stg[q]) : "v"(p));
      }
      if (tid < 32) {
        const unsigned short* p = src + (size_t)(4096 + tid) * 8;
        asm volatile("global_load_dwordx4 %0, %1, off sc0 sc1"
                     : "=v"(stg8) : "v"(p));
      }
    }

    // ---- xs partial (hides staging latency): A from global, B from XP (L2)
    if (t >= iimin && t <= iimin + 94) {
      int j0 = t - ii0, j1 = t - ii1;
      bool ib0 = (j0 >= 0) & (j0 < 64);
      bool ib1 = (j1 >= 0) & (j1 < 64);
      const unsigned short* px0 = xb0 + (ptrdiff_t)j0 * 256;
      const unsigned short* px1 = xb1 + (ptrdiff_t)j1 * 256;
      int kh4 = kh * 4;
#pragma unroll
      for (int ksl = 0; ksl < 4; ksl++) {
        int ksg = kh4 + ksl;
        int kk = ksg * 32 + l4 * 8;
        s16x8 a0 = ib0 ? *(const s16x8*)(px0 + kk) : zz;
        s16x8 a1 = ib1 ? *(const s16x8*)(px1 + kk) : zz;
        const unsigned short* pbx = XPb + (size_t)(ksg * 4) * 512;
#pragma unroll
        for (int ni = 0; ni < 4; ni++) {
          s16x8 b = *(const s16x8*)(pbx + (size_t)ni * 512);
          acc[0][ni] = __builtin_amdgcn_mfma_f32_16x16x32_bf16(a0, b, acc[0][ni], 0, 0, 0);
          acc[1][ni] = __builtin_amdgcn_mfma_f32_16x16x32_bf16(a1, b, acc[1][ni], 0, 0, 0);
        }
      }
    }

    if (t > 0) {
      // ---- drain staging, write LDS (XOR swizzle on byte bits 4-6 by row&7)
      asm volatile("s_waitcnt vmcnt(0)" ::: "memory");
#pragma unroll
      for (int q = 0; q < 8; q++) {
        int raw = (tid + q * 512) * 16;
        int sw = raw ^ (((raw >> 9) & 7) << 4);
        *(i32x4*)((char*)hsl + sw) = stg[q];
      }
      if (tid < 32) {
        int raw = (4096 + tid) * 16;
        int sw = raw ^ (((raw >> 9) & 7) << 4);
        *(i32x4*)((char*)hsl + sw) = stg8;
      }
      __syncthreads();
      // ---- recurrent partial: A from LDS h-slab, B from RP (L2)
      int kh8 = kh * 8;
#pragma unroll
      for (int ksl = 0; ksl < 8; ksl++) {
        int ksg = kh8 + ksl;
        int raw0 = row0 * 512 + ksg * 64 + l4 * 16;
        int raw1 = raw0 + 8192;
        int sw0 = raw0 ^ (((raw0 >> 9) & 7) << 4);
        int sw1 = raw1 ^ (((raw1 >> 9) & 7) << 4);
        s16x8 a0 = *(const s16x8*)((const char*)hsl + sw0);
        s16x8 a1 = (m1 && kh) ? zz : *(const s16x8*)((const char*)hsl + sw1);
        const unsigned short* pbr = RPb + (size_t)(ksg * 4) * 512;
#pragma unroll
        for (int ni = 0; ni < 4; ni++) {
          s16x8 b = *(const s16x8*)(pbr + (size_t)ni * 512);
          acc[0][ni] = __builtin_amdgcn_mfma_f32_16x16x32_bf16(a0, b, acc[0][ni], 0, 0, 0);
          acc[1][ni] = __builtin_amdgcn_mfma_f32_16x16x32_bf16(a1, b, acc[1][ni], 0, 0, 0);
        }
      }
    }

    // ---- K-half reduction via LDS (padded stride 36 floats)
    if (kh == 1) {
#pragma unroll
      for (int ni = 0; ni < 4; ni++)
#pragma unroll
        for (int mi = 0; mi < 2; mi++)
          *(f32x4*)&redbuf[(size_t)(rg * 64 + ni * 16 + l15) * 36 + mi * 16 + l4 * 4] =
              acc[mi][ni];
    }
    __syncthreads();
    if (kh == 0) {
#pragma unroll
      for (int ni = 0; ni < 4; ni++)
#pragma unroll
        for (int mi = 0; mi < 2; mi++) {
          f32x4 p = *(const f32x4*)&redbuf[(size_t)(rg * 64 + ni * 16 + l15) * 36 +
                                           mi * 16 + l4 * 4];
          acc[mi][ni] += p;
        }
      // ---- fused LSTM epilogue; h stores device-coherent (LLC)
      unsigned short* hout = hs + (size_t)t * 524288;
#pragma unroll
      for (int mi = 0; mi < 2; mi++) {
#pragma unroll
        for (int r = 0; r < 4; r++) {
          int R = rbase + mi * 16 + l4 * 4 + r;
          float xi = acc[mi][0][r] + gb0;
          float xf = acc[mi][1][r] + gb1;
          float xg = acc[mi][2][r] + gb2;
          float xo = acc[mi][3][r] + gb3;
          float si = 1.f / (1.f + __expf(-xi));
          float sf = 1.f / (1.f + __expf(-xf));
          float so = 1.f / (1.f + __expf(-xo));
          float tg = 1.f - 2.f / (__expf(2.f * xg) + 1.f);
          float cn = sf * cst[mi * 4 + r] + si * tg;
          cst[mi * 4 + r] = cn;
          float th = 1.f - 2.f / (__expf(2.f * cn) + 1.f);
          unsigned short hv = f2bf(so * th);
          const unsigned short* pst = hout + (size_t)R * 256 + ch;
          asm volatile("global_store_short %0, %1, off sc0 sc1"
                       :: "v"(pst), "v"(hv));
        }
      }
      asm volatile("s_waitcnt vmcnt(0)" ::: "memory");
    }
    __syncthreads();
    // ---- publish step completion (monotone per-slab counter)
    if (tid == 0 && t < 126)
      __hip_atomic_fetch_add(mycnt, 1u, __ATOMIC_RELAXED,
                             __HIP_MEMORY_SCOPE_AGENT);
  }
}

// ---------------------------------------------------------------------------
// gather: out[b,o,hh,j] = hs0[hh+j][row][c0+hh] + (hh>0)*hs1[hh-1+63-j][row][c0+hh-1]
// ---------------------------------------------------------------------------
__global__ __launch_bounds__(256) void gather_kernel(
    const unsigned short* __restrict__ hs, float* __restrict__ out) {
  __shared__ unsigned short slab0[127 * 66 + 2];
  __shared__ unsigned short slab1[127 * 66 + 2];
  int blk = blockIdx.x;                    // bb*256 + o
  int bb = blk >> 8, o = blk & 255;
  int row = bb * 64 + (o >> 2);
  int c0 = (o & 3) * 64;
  int tid = threadIdx.x;
  for (int idx = tid; idx < 127 * 32; idx += 256) {
    int tt = idx >> 5, cu = idx & 31;
    unsigned v0 = *(const unsigned*)(hs + ((size_t)tt * RT_ + row) * 256 + c0 + cu * 2);
    unsigned v1 = *(const unsigned*)(hs + ((size_t)tt * RT_ + 1024 + row) * 256 + c0 + cu * 2);
    *(unsigned*)(slab0 + tt * 66 + cu * 2) = v0;
    *(unsigned*)(slab1 + tt * 66 + cu * 2) = v1;
  }
  __syncthreads();
  int j = tid & 63;
  int hh0 = (tid >> 6) * 16;
  float* ob = out + (size_t)blk * 4096;
  for (int hh = hh0; hh < hh0 + 16; hh++) {
    float v = bf2f(slab0[(hh + j) * 66 + hh]);
    if (hh > 0) v += bf2f(slab1[(hh - 1 + 63 - j) * 66 + (hh - 1)]);
    ob[hh * 64 + j] = v;
  }
}

// ---------------------------------------------------------------------------
extern "C" void kernel_launch(void* const* d_in, const int* in_sizes, int n_in,
                              void* d_out, int out_size, void* d_ws, size_t ws_size,
                              hipStream_t stream) {
  const float* x     = (const float*)d_in[0];
  const float* w_i2s = (const float*)d_in[1];
  const float* b_i2s = (const float*)d_in[2];
  const float* w_ih  = (const float*)d_in[3];
  const float* b_ih  = (const float*)d_in[4];
  const float* b_hh  = (const float*)d_in[5];
  const float* k0    = (const float*)d_in[6];
  const float* k1    = (const float*)d_in[7];
  const float* b_s2s = (const float*)d_in[8];
  float* out = (float*)d_out;

  char* ws = (char*)d_ws;
  // workspace map (bytes)
  float*          wm     = (float*)(ws + 0);                 //   256 KiB
  float*          cvec   = (float*)(ws + 262144);            //     1 KiB
  float*          gbias  = (float*)(ws + 263168);            //     4 KiB
  float*          gbias2 = (float*)(ws + 267264);            //     4 KiB
  unsigned*       cnt    = (unsigned*)(ws + 271360);         //     1 KiB (16x64B)
  unsigned short* XP     = (unsigned short*)(ws + 272384);   //   512 KiB
  unsigned short* RP     = (unsigned short*)(ws + 796672);   //     1 MiB
  unsigned short* xs     = (unsigned short*)(ws + 1845248);  //    64 MiB
  unsigned short* hs     = (unsigned short*)(ws + 68954112); //   127 MiB
  const size_t NEEDED = 202123264;
  if (ws_size < NEEDED) return;  // workspace too small; fail loudly via mismatch

  prep_kernel<<<1286, 256, 0, stream>>>(w_i2s, b_i2s, w_ih, b_ih, b_hh, b_s2s,
                                        wm, XP, cvec, gbias, cnt);
  prep2_kernel<<<256, 256, 0, stream>>>(w_ih, k0, k1, cvec, gbias, RP, gbias2);
  xs_kernel<<<1024, 256, 65536, stream>>>(x, wm, xs);

  {
    const unsigned short* a0 = xs;
    const unsigned short* a1 = RP;
    const unsigned short* a2 = XP;
    const float*          a3 = gbias2;
    unsigned short*       a4 = hs;
    unsigned*             a5 = cnt;
    void* kargs[6] = {(void*)&a0, (void*)&a1, (void*)&a2,
                      (void*)&a3, (void*)&a4, (void*)&a5};
    hipLaunchCooperativeKernel((const void*)loop_kernel, dim3(NBLK), dim3(512),
                               kargs, 0, stream);
  }

  gather_kernel<<<4096, 256, 0, stream>>>(hs, out);
}

// Round 3
// 1131.447 us; speedup vs baseline: 3.0287x; 1.5570x over previous
//
#include <hip/hip_runtime.h>
#include <cstdint>
#include <cstddef>

// Problem constants
#define BB_ 16
#define HH_ 64
#define WW_ 64
#define CC_ 256
#define WD_ 127
#define RPD 1024   // rows per direction (B*H)
#define RT_ 2048   // total rows (both directions stacked)
#define NBLK 256   // persistent grid size

typedef float  f32x4 __attribute__((ext_vector_type(4)));
typedef short  s16x8 __attribute__((ext_vector_type(8)));
typedef int    i32x4 __attribute__((ext_vector_type(4)));

__device__ __forceinline__ unsigned short f2bf(float f) {
  unsigned u = __float_as_uint(f);
  u += 0x7fffu + ((u >> 16) & 1u);   // round-to-nearest-even
  return (unsigned short)(u >> 16);
}
__device__ __forceinline__ float bf2f(unsigned short h) {
  return __uint_as_float(((unsigned)h) << 16);
}

// ---------------------------------------------------------------------------
// prep: masked i2s weights (fp32), XP = xs-B-operand pack (fragment-major:
// XP[chb][ks(8)][ni(4)][lane(64)][8]), fused biases, block counters -> 0.
// Gate-interleave: n = chb*64 + g*16 + cl, original row j = g*256 + chb*16+cl.
// ---------------------------------------------------------------------------
__global__ __launch_bounds__(256) void prep_kernel(
    const float* __restrict__ w_i2s, const float* __restrict__ b_i2s,
    const float* __restrict__ w_ih,  const float* __restrict__ b_ih,
    const float* __restrict__ b_hh,  const float* __restrict__ b_s2s,
    float* __restrict__ wm, unsigned short* __restrict__ XP,
    float* __restrict__ cvec, float* __restrict__ gbias,
    unsigned* __restrict__ cnt) {
  int idx = blockIdx.x * 256 + threadIdx.x;
  if (idx < 65536) {                       // wm[c][cin], masked
    int c = idx >> 8, ci = idx & 255;
    wm[idx] = ((ci % 3) <= (c % 3)) ? w_i2s[idx] : 0.0f;
  }
  int i3 = idx - 65536;                    // XP pack of w_ih
  if (i3 >= 0 && i3 < 262144) {
    int n = i3 >> 8, k = i3 & 255;
    int chb = n >> 6, g = (n >> 4) & 3, cl = n & 15;
    int j = g * 256 + chb * 16 + cl;
    float val = w_ih[j * 256 + k];
    int ks = k >> 5, l4k = (k >> 3) & 3, e = k & 7;
    size_t o = (size_t)chb * 16384 + (size_t)(ks * 4 + g) * 512 +
               (size_t)(l4k * 16 + cl) * 8 + e;
    XP[o] = f2bf(val);
  }
  int i4 = idx - 327680;                   // cvec = b_i2s + b_s2s
  if (i4 >= 0 && i4 < 256) cvec[i4] = b_i2s[i4] + b_s2s[i4];
  int i5 = idx - 327936;                   // gbias[n] = b_ih[j] + b_hh[j]
  if (i5 >= 0 && i5 < 1024) {
    int chb = i5 >> 6, g = (i5 >> 4) & 3, cl = i5 & 15;
    int j = g * 256 + chb * 16 + cl;
    gbias[i5] = b_ih[j] + b_hh[j];
  }
  int i6 = idx - 328960;                   // 32 slabs x 8 blocks, 64B spacing
  if (i6 >= 0 && i6 < 256) cnt[i6 * 16] = 0u;
}

// ---------------------------------------------------------------------------
// prep2: combined recurrent weights, packed fragment-major into RP:
//   k2 <  256 : M0[n][c] = sum_k w_ih[j(n)][k] * k0[k][c]   (pairs h_prev)
//   k2 >= 256 : M1[n][c] = sum_k w_ih[j(n)][k] * k1[k][c]   (pairs h_next)
// RP[chb][ks(16)][ni(4)][lane(64)][8] bf16.  gbias2 = gbias + W2 @ cvec.
// ---------------------------------------------------------------------------
__global__ __launch_bounds__(256) void prep2_kernel(
    const float* __restrict__ w_ih, const float* __restrict__ k0,
    const float* __restrict__ k1,   const float* __restrict__ cvec,
    const float* __restrict__ gbias, unsigned short* __restrict__ RP,
    float* __restrict__ gbias2) {
  __shared__ float wr[4][256];
  __shared__ float red[256];
  int bid = blockIdx.x, tid = threadIdx.x;
#pragma unroll
  for (int q = 0; q < 4; q++) {
    int n = bid * 4 + q;
    int chb = n >> 6, g = (n >> 4) & 3, cl = n & 15;
    int j = g * 256 + chb * 16 + cl;
    wr[q][tid] = w_ih[j * 256 + tid];
  }
  __syncthreads();
  int c = tid;
  float a0[4] = {0.f, 0.f, 0.f, 0.f}, a1[4] = {0.f, 0.f, 0.f, 0.f};
  for (int k = 0; k < 256; k++) {
    float v0 = k0[k * 256 + c], v1 = k1[k * 256 + c];
#pragma unroll
    for (int q = 0; q < 4; q++) {
      a0[q] = fmaf(wr[q][k], v0, a0[q]);
      a1[q] = fmaf(wr[q][k], v1, a1[q]);
    }
  }
  int ks0 = c >> 5, l40 = (c >> 3) & 3, e0 = c & 7;
#pragma unroll
  for (int q = 0; q < 4; q++) {
    int n = bid * 4 + q;
    int vv = n >> 6, nii = (n >> 4) & 3, ll = n & 15;
    size_t i0 = (size_t)vv * 32768 + (size_t)(ks0 * 4 + nii) * 512 +
                (size_t)(l40 * 16 + ll) * 8 + e0;
    size_t i1 = (size_t)vv * 32768 + (size_t)((ks0 + 8) * 4 + nii) * 512 +
                (size_t)(l40 * 16 + ll) * 8 + e0;
    RP[i0] = f2bf(a0[q]);
    RP[i1] = f2bf(a1[q]);
  }
  float cv = cvec[c];
#pragma unroll
  for (int q = 0; q < 4; q++) {
    red[tid] = wr[q][tid] * cv;
    __syncthreads();
    for (int s = 128; s > 0; s >>= 1) {
      if (tid < s) red[tid] += red[tid + s];
      __syncthreads();
    }
    if (tid == 0) { int n = bid * 4 + q; gbias2[n] = gbias[n] + red[0]; }
    __syncthreads();
  }
}

// ---------------------------------------------------------------------------
// xs: banded masked 1x1 conv, computed once per (bb,i), reused for both
// directions. Output xs[dir][row][j][c] bf16 (c contiguous), j = t - i.
// ---------------------------------------------------------------------------
__global__ __launch_bounds__(256) void xs_kernel(
    const float* __restrict__ x, const float* __restrict__ wm,
    unsigned short* __restrict__ xs) {
  extern __shared__ float xt[];                   // [256 cin][64 j]
  int blk = blockIdx.x;                           // bb*64 + i
  int bb = blk >> 6, ii = blk & 63;
  int tid = threadIdx.x;
  {
    const float4* src = (const float4*)(x + (((size_t)bb * 256 + tid) * 64 + ii) * 64);
    float4* dst = (float4*)(xt + tid * 64);
#pragma unroll
    for (int q = 0; q < 16; q++) dst[q] = src[q];
  }
  __syncthreads();

  int cp = tid & 127, c0 = cp * 2;
  int j0 = (tid >> 7) * 32;                       // wave-uniform (0 or 32)
  float acc0[32], acc1[32];
#pragma unroll
  for (int q = 0; q < 32; q++) { acc0[q] = 0.f; acc1[q] = 0.f; }

  for (int c4 = 0; c4 < 64; c4++) {
    float4 wa = *(const float4*)(wm + c0 * 256 + c4 * 4);
    float4 wb = *(const float4*)(wm + (c0 + 1) * 256 + c4 * 4);
    float wav[4] = {wa.x, wa.y, wa.z, wa.w};
    float wbv[4] = {wb.x, wb.y, wb.z, wb.w};
#pragma unroll
    for (int j4 = 0; j4 < 8; j4++) {
#pragma unroll
      for (int i = 0; i < 4; i++) {
        float4 xv = *(const float4*)(xt + (c4 * 4 + i) * 64 + j0 + j4 * 4);
        acc0[j4 * 4 + 0] = fmaf(wav[i], xv.x, acc0[j4 * 4 + 0]);
        acc0[j4 * 4 + 1] = fmaf(wav[i], xv.y, acc0[j4 * 4 + 1]);
        acc0[j4 * 4 + 2] = fmaf(wav[i], xv.z, acc0[j4 * 4 + 2]);
        acc0[j4 * 4 + 3] = fmaf(wav[i], xv.w, acc0[j4 * 4 + 3]);
        acc1[j4 * 4 + 0] = fmaf(wbv[i], xv.x, acc1[j4 * 4 + 0]);
        acc1[j4 * 4 + 1] = fmaf(wbv[i], xv.y, acc1[j4 * 4 + 1]);
        acc1[j4 * 4 + 2] = fmaf(wbv[i], xv.z, acc1[j4 * 4 + 2]);
        acc1[j4 * 4 + 3] = fmaf(wbv[i], xv.w, acc1[j4 * 4 + 3]);
      }
    }
  }
  size_t row = (size_t)blk;
#pragma unroll
  for (int q = 0; q < 32; q++) {
    int j = j0 + q;
    unsigned pv = (unsigned)f2bf(acc0[q]) | ((unsigned)f2bf(acc1[q]) << 16);
    *(unsigned*)(xs + ((row * 64 + j) * 256 + c0)) = pv;                      // dir0
    *(unsigned*)(xs + (16777216u + (row * 64 + (63 - j)) * 256 + c0)) = pv;   // dir1
  }
}

// ---------------------------------------------------------------------------
// loop: persistent, fence-free. 256 blocks x 512 thr (1/CU).
// Block = slab s (64 rows) x vgroup v (32 ch = 128 gate-cols); 8 waves =
// 2 rowgroups(32r) x 2 chb-halves x 2 K-halves. rec-B weights in VGPRs for
// the whole loop; xs-B in LDS; h[t-1] slab staged via sc0sc1 loads into
// XOR-swizzled LDS; redbuf (stride 20) for the K-half exchange; per-block
// monotone counters (8/slab) with per-wave publish and all-lane polling.
// Mapping: s = (bid&7)*4 + ((bid>>3)&3) groups 4 whole slabs per XCD so xs
// reads dedupe in that XCD's L2 (perf heuristic only; correctness via sc1).
// ---------------------------------------------------------------------------
__global__ __launch_bounds__(512, 2) void loop_kernel(
    const unsigned short* __restrict__ xs,
    const unsigned short* __restrict__ RP,
    const unsigned short* __restrict__ XP,
    const float* __restrict__ gbias2,
    unsigned short* __restrict__ hs,
    unsigned* __restrict__ cnt) {
  __shared__ __align__(16) unsigned short stg[16640];   // 65 rows x 512 B, swizzled
  __shared__ __align__(16) unsigned short xb[32768];    // 64 KiB xs-B fragments
  __shared__ __align__(16) float redbuf[10240];         // 40 KiB, stride 20

  int bid = blockIdx.x;
  int v = bid >> 5;                              // block-in-slab / vgroup 0..7
  int s = (bid & 7) * 4 + ((bid >> 3) & 3);      // slab 0..31 (XCD-grouped)
  int r0 = s * 64;
  int tid = threadIdx.x, lane = tid & 63, w = tid >> 6;
  int rg = w >> 2, nh = (w >> 1) & 1, kh = w & 1;
  int l15 = lane & 15, l4 = lane >> 4;
  int chb = v * 2 + nh;
  int rbase = r0 + rg * 32;

  // ---- prologue: xs-B fragments (both chb halves) -> LDS, frag-major
  for (int idx = tid; idx < 4096; idx += 512) {
    int frag = idx >> 6, ln = idx & 63;
    int c2 = frag >> 5, rem = frag & 31;
    *(s16x8*)(xb + (size_t)idx * 8) =
        *(const s16x8*)(XP + (size_t)(v * 2 + c2) * 16384 + (size_t)rem * 512 +
                        (size_t)ln * 8);
  }
  // ---- rec-B fragments -> registers (step-invariant)
  s16x8 RB[8][4];
  {
    const unsigned short* RPb = RP + (size_t)chb * 32768 + (size_t)lane * 8;
#pragma unroll
    for (int ksl = 0; ksl < 8; ksl++)
#pragma unroll
      for (int ni = 0; ni < 4; ni++)
        RB[ksl][ni] =
            *(const s16x8*)(RPb + (size_t)((kh * 8 + ksl) * 4 + ni) * 512);
  }
  float gb[4];
#pragma unroll
  for (int ni = 0; ni < 4; ni++) gb[ni] = gbias2[chb * 64 + ni * 16 + l15];
  int ch = chb * 16 + l15;
  float cst[4] = {0.f, 0.f, 0.f, 0.f};

  int Rl0 = rbase + l15, Rl1 = Rl0 + 16;
  const unsigned short* xg0 =
      xs + (size_t)(Rl0 >> 10) * 16777216u + (size_t)(Rl0 & 1023) * 16384;
  const unsigned short* xg1 =
      xs + (size_t)(Rl1 >> 10) * 16777216u + (size_t)(Rl1 & 1023) * 16384;
  int ii0 = rg * 32 + l15, ii1 = ii0 + 16;
  int tlo = rg * 32, thi = rg * 32 + 94;
  bool km1 = kh && ((s & 15) == 15) && (rg == 1) && (l15 == 15);
  bool nbwave = (w == 0) && ((s & 15) != 15);
  unsigned* myc = cnt + ((s * 8 + (lane & 7)) * 16);
  unsigned* nbc = cnt + (((s + 1) * 8 + (lane & 7)) * 16);
  unsigned* pubc = cnt + ((s * 8 + v) * 16);
  int rsw = ((l15 + kh) & 7) << 4;
  int ar0b = (rg * 32 + l15 + kh) * 512;   // stage byte base, mi0 rows
  int ar1b = ar0b + 8192;                   // +16 rows (mi1)
  const s16x8 zz = {0, 0, 0, 0, 0, 0, 0, 0};

  __syncthreads();   // xb ready

  for (int t = 0; t < 127; ++t) {
    f32x4 accA[4], accB[4];
#pragma unroll
    for (int ni = 0; ni < 4; ni++) {
      accA[ni] = (f32x4){0.f, 0.f, 0.f, 0.f};
      accB[ni] = (f32x4){0.f, 0.f, 0.f, 0.f};
    }
    // ---- xs partial (independent of h -> fills the dependency wait)
    if (t >= tlo && t <= thi) {
      int j0 = t - ii0, j1 = t - ii1;
      bool ib0 = ((unsigned)j0 < 64u), ib1 = ((unsigned)j1 < 64u);
      const unsigned short* px0 = xg0 + (ptrdiff_t)j0 * 256;
      const unsigned short* px1 = xg1 + (ptrdiff_t)j1 * 256;
#pragma unroll
      for (int ksl = 0; ksl < 4; ksl++) {
        int kk = (kh * 4 + ksl) * 32 + l4 * 8;
        s16x8 a0 = ib0 ? *(const s16x8*)(px0 + kk) : zz;
        s16x8 a1 = ib1 ? *(const s16x8*)(px1 + kk) : zz;
        const unsigned short* bb =
            xb + ((size_t)((nh * 8 + kh * 4 + ksl) * 4) * 64 + (size_t)lane) * 8;
#pragma unroll
        for (int ni = 0; ni < 4; ni++) {
          s16x8 b = *(const s16x8*)(bb + (size_t)ni * 512);
          accA[ni] = __builtin_amdgcn_mfma_f32_16x16x32_bf16(a0, b, accA[ni], 0, 0, 0);
          accB[ni] = __builtin_amdgcn_mfma_f32_16x16x32_bf16(a1, b, accB[ni], 0, 0, 0);
        }
      }
    }

    if (t > 0) {
      // ---- spin: 8 block-counters of own slab (+ neighbor for halo wave)
      unsigned tgt = (unsigned)t * 8u;
      while (true) {
        unsigned c_ = __hip_atomic_load(myc, __ATOMIC_RELAXED,
                                        __HIP_MEMORY_SCOPE_AGENT);
        if (__all(c_ >= tgt)) break;
        __builtin_amdgcn_s_sleep(1);
      }
      if (nbwave) {
        while (true) {
          unsigned c_ = __hip_atomic_load(nbc, __ATOMIC_RELAXED,
                                          __HIP_MEMORY_SCOPE_AGENT);
          if (__all(c_ >= tgt)) break;
          __builtin_amdgcn_s_sleep(1);
        }
      }
      // ---- stage h[t-1] rows r0..r0+64 (device-coherent loads)
      const unsigned short* src = hs + (size_t)(t - 1) * 524288 + (size_t)r0 * 256;
      i32x4 sv0, sv1, sv2, sv3, sv4;
      asm volatile("global_load_dwordx4 %0, %1, off sc0 sc1"
                   : "=v"(sv0) : "v"(src + (size_t)tid * 8));
      asm volatile("global_load_dwordx4 %0, %1, off sc0 sc1"
                   : "=v"(sv1) : "v"(src + (size_t)(tid + 512) * 8));
      asm volatile("global_load_dwordx4 %0, %1, off sc0 sc1"
                   : "=v"(sv2) : "v"(src + (size_t)(tid + 1024) * 8));
      asm volatile("global_load_dwordx4 %0, %1, off sc0 sc1"
                   : "=v"(sv3) : "v"(src + (size_t)(tid + 1536) * 8));
      if (tid < 32)
        asm volatile("global_load_dwordx4 %0, %1, off sc0 sc1"
                     : "=v"(sv4) : "v"(src + (size_t)(tid + 2048) * 8));
      asm volatile("s_waitcnt vmcnt(0)" ::: "memory");
      __builtin_amdgcn_sched_barrier(0);
      {
        int rA = tid >> 5, cA = (tid & 31) * 16;
        *(i32x4*)((char*)stg + (rA +  0) * 512 + (cA ^ (((rA +  0) & 7) << 4))) = sv0;
        *(i32x4*)((char*)stg + (rA + 16) * 512 + (cA ^ (((rA + 16) & 7) << 4))) = sv1;
        *(i32x4*)((char*)stg + (rA + 32) * 512 + (cA ^ (((rA + 32) & 7) << 4))) = sv2;
        *(i32x4*)((char*)stg + (rA + 48) * 512 + (cA ^ (((rA + 48) & 7) << 4))) = sv3;
        if (tid < 32)
          *(i32x4*)((char*)stg + 64 * 512 + (tid * 16)) = sv4;   // row64 & 7 == 0
      }
      __syncthreads();
      // ---- recurrent MFMAs: A from staged LDS, B from registers
#pragma unroll
      for (int ksl = 0; ksl < 8; ksl++) {
        int cb = ((ksl * 64 + l4 * 16) ^ rsw);
        s16x8 a0 = *(const s16x8*)((const char*)stg + ar0b + cb);
        s16x8 a1 = *(const s16x8*)((const char*)stg + ar1b + cb);
        a1 = km1 ? zz : a1;
#pragma unroll
        for (int ni = 0; ni < 4; ni++) {
          accA[ni] = __builtin_amdgcn_mfma_f32_16x16x32_bf16(a0, RB[ksl][ni], accA[ni], 0, 0, 0);
          accB[ni] = __builtin_amdgcn_mfma_f32_16x16x32_bf16(a1, RB[ksl][ni], accB[ni], 0, 0, 0);
        }
      }
    }

    // ---- K-half exchange: send partner's mi, keep own (mi = kh)
    {
      float* wsl = redbuf + (size_t)(((rg * 2 + nh) * 2 + (kh ^ 1)) * 1280);
#pragma unroll
      for (int ni = 0; ni < 4; ni++) {
        f32x4 wv = kh ? accA[ni] : accB[ni];
        *(f32x4*)(wsl + (size_t)((ni * 16 + l15) * 20 + l4 * 4)) = wv;
      }
    }
    __syncthreads();
    f32x4 ov[4];
    {
      const float* rsl = redbuf + (size_t)(((rg * 2 + nh) * 2 + kh) * 1280);
#pragma unroll
      for (int ni = 0; ni < 4; ni++) {
        f32x4 p = *(const f32x4*)(rsl + (size_t)((ni * 16 + l15) * 20 + l4 * 4));
        ov[ni] = (kh ? accB[ni] : accA[ni]) + p;
      }
    }
    // ---- fused LSTM epilogue on own 16 rows (mi = kh); stores via LLC
    unsigned short* hout = hs + (size_t)t * 524288;
#pragma unroll
    for (int r = 0; r < 4; r++) {
      int R = rbase + kh * 16 + l4 * 4 + r;
      float xi = ov[0][r] + gb[0];
      float xf = ov[1][r] + gb[1];
      float xg_ = ov[2][r] + gb[2];
      float xo = ov[3][r] + gb[3];
      float si = 1.f / (1.f + __expf(-xi));
      float sf = 1.f / (1.f + __expf(-xf));
      float so = 1.f / (1.f + __expf(-xo));
      float tg = 1.f - 2.f / (__expf(2.f * xg_) + 1.f);
      float cn = sf * cst[r] + si * tg;
      cst[r] = cn;
      float th = 1.f - 2.f / (__expf(2.f * cn) + 1.f);
      unsigned short hv = f2bf(so * th);
      const unsigned short* pst = hout + (size_t)R * 256 + ch;
      asm volatile("global_store_short %0, %1, off sc0 sc1"
                   :: "v"(pst), "v"(hv));
    }
    asm volatile("s_waitcnt vmcnt(0)" ::: "memory");
    __builtin_amdgcn_sched_barrier(0);
    if (lane == 0)
      __hip_atomic_fetch_add(pubc, 1u, __ATOMIC_RELAXED,
                             __HIP_MEMORY_SCOPE_AGENT);
  }
}

// ---------------------------------------------------------------------------
// gather: out[b,o,hh,j] = hs0[hh+j][row][c0+hh] + (hh>0)*hs1[hh-1+63-j][row][c0+hh-1]
// ---------------------------------------------------------------------------
__global__ __launch_bounds__(256) void gather_kernel(
    const unsigned short* __restrict__ hs, float* __restrict__ out) {
  __shared__ unsigned short slab0[127 * 66 + 2];
  __shared__ unsigned short slab1[127 * 66 + 2];
  int blk = blockIdx.x;                    // bb*256 + o
  int bb = blk >> 8, o = blk & 255;
  int row = bb * 64 + (o >> 2);
  int c0 = (o & 3) * 64;
  int tid = threadIdx.x;
  for (int idx = tid; idx < 127 * 32; idx += 256) {
    int tt = idx >> 5, cu = idx & 31;
    unsigned v0 = *(const unsigned*)(hs + ((size_t)tt * RT_ + row) * 256 + c0 + cu * 2);
    unsigned v1 = *(const unsigned*)(hs + ((size_t)tt * RT_ + 1024 + row) * 256 + c0 + cu * 2);
    *(unsigned*)(slab0 + tt * 66 + cu * 2) = v0;
    *(unsigned*)(slab1 + tt * 66 + cu * 2) = v1;
  }
  __syncthreads();
  int j = tid & 63;
  int hh0 = (tid >> 6) * 16;
  float* ob = out + (size_t)blk * 4096;
  for (int hh = hh0; hh < hh0 + 16; hh++) {
    float v = bf2f(slab0[(hh + j) * 66 + hh]);
    if (hh > 0) v += bf2f(slab1[(hh - 1 + 63 - j) * 66 + (hh - 1)]);
    ob[hh * 64 + j] = v;
  }
}

// ---------------------------------------------------------------------------
extern "C" void kernel_launch(void* const* d_in, const int* in_sizes, int n_in,
                              void* d_out, int out_size, void* d_ws, size_t ws_size,
                              hipStream_t stream) {
  const float* x     = (const float*)d_in[0];
  const float* w_i2s = (const float*)d_in[1];
  const float* b_i2s = (const float*)d_in[2];
  const float* w_ih  = (const float*)d_in[3];
  const float* b_ih  = (const float*)d_in[4];
  const float* b_hh  = (const float*)d_in[5];
  const float* k0    = (const float*)d_in[6];
  const float* k1    = (const float*)d_in[7];
  const float* b_s2s = (const float*)d_in[8];
  float* out = (float*)d_out;

  char* ws = (char*)d_ws;
  // workspace map (bytes)
  float*          wm     = (float*)(ws + 0);                 //   256 KiB
  float*          cvec   = (float*)(ws + 262144);            //     1 KiB
  float*          gbias  = (float*)(ws + 263168);            //     4 KiB
  float*          gbias2 = (float*)(ws + 267264);            //     4 KiB
  unsigned*       cnt    = (unsigned*)(ws + 271360);         //    16 KiB (256x64B)
  unsigned short* XP     = (unsigned short*)(ws + 287744);   //   512 KiB
  unsigned short* RP     = (unsigned short*)(ws + 812032);   //     1 MiB
  unsigned short* xs     = (unsigned short*)(ws + 1860608);  //    64 MiB
  unsigned short* hs     = (unsigned short*)(ws + 68969472); //   127 MiB
  const size_t NEEDED = 202138624;
  if (ws_size < NEEDED) return;  // workspace too small; fail loudly via mismatch

  prep_kernel<<<1286, 256, 0, stream>>>(w_i2s, b_i2s, w_ih, b_ih, b_hh, b_s2s,
                                        wm, XP, cvec, gbias, cnt);
  prep2_kernel<<<256, 256, 0, stream>>>(w_ih, k0, k1, cvec, gbias, RP, gbias2);
  xs_kernel<<<1024, 256, 65536, stream>>>(x, wm, xs);

  {
    const unsigned short* a0 = xs;
    const unsigned short* a1 = RP;
    const unsigned short* a2 = XP;
    const float*          a3 = gbias2;
    unsigned short*       a4 = hs;
    unsigned*             a5 = cnt;
    void* kargs[6] = {(void*)&a0, (void*)&a1, (void*)&a2,
                      (void*)&a3, (void*)&a4, (void*)&a5};
    hipLaunchCooperativeKernel((const void*)loop_kernel, dim3(NBLK), dim3(512),
                               kargs, 0, stream);
  }

  gather_kernel<<<4096, 256, 0, stream>>>(hs, out);
}

// Round 5
// 1086.246 us; speedup vs baseline: 3.1547x; 1.0416x over previous
//
#include <hip/hip_runtime.h>
#include <cstdint>
#include <cstddef>

// Problem constants
#define BB_ 16
#define HH_ 64
#define WW_ 64
#define CC_ 256
#define WD_ 127
#define RPD 1024   // rows per direction (B*H)
#define RT_ 2048   // total rows (both directions stacked)
#define NBLK 256   // persistent grid size

typedef float  f32x4 __attribute__((ext_vector_type(4)));
typedef short  s16x8 __attribute__((ext_vector_type(8)));
typedef int    i32x4 __attribute__((ext_vector_type(4)));

__device__ __forceinline__ unsigned short f2bf(float f) {
  unsigned u = __float_as_uint(f);
  u += 0x7fffu + ((u >> 16) & 1u);   // round-to-nearest-even
  return (unsigned short)(u >> 16);
}
__device__ __forceinline__ float bf2f(unsigned short h) {
  return __uint_as_float(((unsigned)h) << 16);
}

__device__ __forceinline__ void gl_lds16(const unsigned short* g,
                                         unsigned short* l) {
  __builtin_amdgcn_global_load_lds(
      (const __attribute__((address_space(1))) void*)g,
      (__attribute__((address_space(3))) void*)l, 16, 0, 0);
}

// ---------------------------------------------------------------------------
// prep: masked i2s weights (fp32), XP = xs-B-operand pack (fragment-major:
// XP[chb][ks(8)][ni(4)][lane(64)][8]), fused biases, tag array -> 0.
// Gate-interleave: n = chb*64 + g*16 + cl, original row j = g*256 + chb*16+cl.
// ---------------------------------------------------------------------------
__global__ __launch_bounds__(256) void prep_kernel(
    const float* __restrict__ w_i2s, const float* __restrict__ b_i2s,
    const float* __restrict__ w_ih,  const float* __restrict__ b_ih,
    const float* __restrict__ b_hh,  const float* __restrict__ b_s2s,
    float* __restrict__ wm, unsigned short* __restrict__ XP,
    float* __restrict__ cvec, float* __restrict__ gbias,
    unsigned* __restrict__ tags) {
  int idx = blockIdx.x * 256 + threadIdx.x;
  if (idx < 65536) {                       // wm[c][cin], masked
    int c = idx >> 8, ci = idx & 255;
    wm[idx] = ((ci % 3) <= (c % 3)) ? w_i2s[idx] : 0.0f;
  }
  int i3 = idx - 65536;                    // XP pack of w_ih
  if (i3 >= 0 && i3 < 262144) {
    int n = i3 >> 8, k = i3 & 255;
    int chb = n >> 6, g = (n >> 4) & 3, cl = n & 15;
    int j = g * 256 + chb * 16 + cl;
    float val = w_ih[j * 256 + k];
    int ks = k >> 5, l4k = (k >> 3) & 3, e = k & 7;
    size_t o = (size_t)chb * 16384 + (size_t)(ks * 4 + g) * 512 +
               (size_t)(l4k * 16 + cl) * 8 + e;
    XP[o] = f2bf(val);
  }
  int i4 = idx - 327680;                   // cvec = b_i2s + b_s2s
  if (i4 >= 0 && i4 < 256) cvec[i4] = b_i2s[i4] + b_s2s[i4];
  int i5 = idx - 327936;                   // gbias[n] = b_ih[j] + b_hh[j]
  if (i5 >= 0 && i5 < 1024) {
    int chb = i5 >> 6, g = (i5 >> 4) & 3, cl = i5 & 15;
    int j = g * 256 + chb * 16 + cl;
    gbias[i5] = b_ih[j] + b_hh[j];
  }
  int i6 = idx - 328960;                   // tags[32][16]
  if (i6 >= 0 && i6 < 512) tags[i6] = 0u;
}

// ---------------------------------------------------------------------------
// prep2: combined recurrent weights, packed fragment-major into RP:
//   k2 <  256 : M0[n][c] = sum_k w_ih[j(n)][k] * k0[k][c]   (pairs h_prev)
//   k2 >= 256 : M1[n][c] = sum_k w_ih[j(n)][k] * k1[k][c]   (pairs h_next)
// RP[chb][ks(16)][ni(4)][lane(64)][8] bf16.  gbias2 = gbias + W2 @ cvec.
// ---------------------------------------------------------------------------
__global__ __launch_bounds__(256) void prep2_kernel(
    const float* __restrict__ w_ih, const float* __restrict__ k0,
    const float* __restrict__ k1,   const float* __restrict__ cvec,
    const float* __restrict__ gbias, unsigned short* __restrict__ RP,
    float* __restrict__ gbias2) {
  __shared__ float wr[4][256];
  __shared__ float red[256];
  int bid = blockIdx.x, tid = threadIdx.x;
#pragma unroll
  for (int q = 0; q < 4; q++) {
    int n = bid * 4 + q;
    int chb = n >> 6, g = (n >> 4) & 3, cl = n & 15;
    int j = g * 256 + chb * 16 + cl;
    wr[q][tid] = w_ih[j * 256 + tid];
  }
  __syncthreads();
  int c = tid;
  float a0[4] = {0.f, 0.f, 0.f, 0.f}, a1[4] = {0.f, 0.f, 0.f, 0.f};
  for (int k = 0; k < 256; k++) {
    float v0 = k0[k * 256 + c], v1 = k1[k * 256 + c];
#pragma unroll
    for (int q = 0; q < 4; q++) {
      a0[q] = fmaf(wr[q][k], v0, a0[q]);
      a1[q] = fmaf(wr[q][k], v1, a1[q]);
    }
  }
  int ks0 = c >> 5, l40 = (c >> 3) & 3, e0 = c & 7;
#pragma unroll
  for (int q = 0; q < 4; q++) {
    int n = bid * 4 + q;
    int vv = n >> 6, nii = (n >> 4) & 3, ll = n & 15;
    size_t i0 = (size_t)vv * 32768 + (size_t)(ks0 * 4 + nii) * 512 +
                (size_t)(l40 * 16 + ll) * 8 + e0;
    size_t i1 = (size_t)vv * 32768 + (size_t)((ks0 + 8) * 4 + nii) * 512 +
                (size_t)(l40 * 16 + ll) * 8 + e0;
    RP[i0] = f2bf(a0[q]);
    RP[i1] = f2bf(a1[q]);
  }
  float cv = cvec[c];
#pragma unroll
  for (int q = 0; q < 4; q++) {
    red[tid] = wr[q][tid] * cv;
    __syncthreads();
    for (int s = 128; s > 0; s >>= 1) {
      if (tid < s) red[tid] += red[tid + s];
      __syncthreads();
    }
    if (tid == 0) { int n = bid * 4 + q; gbias2[n] = gbias[n] + red[0]; }
    __syncthreads();
  }
}

// ---------------------------------------------------------------------------
// xs: banded masked 1x1 conv, computed once per (bb,i), reused for both
// directions. Output xs[dir][row][j][c] bf16 (c contiguous), j = t - i.
// ---------------------------------------------------------------------------
__global__ __launch_bounds__(256) void xs_kernel(
    const float* __restrict__ x, const float* __restrict__ wm,
    unsigned short* __restrict__ xs) {
  extern __shared__ float xt[];                   // [256 cin][64 j]
  int blk = blockIdx.x;                           // bb*64 + i
  int bb = blk >> 6, ii = blk & 63;
  int tid = threadIdx.x;
  {
    const float4* src = (const float4*)(x + (((size_t)bb * 256 + tid) * 64 + ii) * 64);
    float4* dst = (float4*)(xt + tid * 64);
#pragma unroll
    for (int q = 0; q < 16; q++) dst[q] = src[q];
  }
  __syncthreads();

  int cp = tid & 127, c0 = cp * 2;
  int j0 = (tid >> 7) * 32;                       // wave-uniform (0 or 32)
  float acc0[32], acc1[32];
#pragma unroll
  for (int q = 0; q < 32; q++) { acc0[q] = 0.f; acc1[q] = 0.f; }

  for (int c4 = 0; c4 < 64; c4++) {
    float4 wa = *(const float4*)(wm + c0 * 256 + c4 * 4);
    float4 wb = *(const float4*)(wm + (c0 + 1) * 256 + c4 * 4);
    float wav[4] = {wa.x, wa.y, wa.z, wa.w};
    float wbv[4] = {wb.x, wb.y, wb.z, wb.w};
#pragma unroll
    for (int j4 = 0; j4 < 8; j4++) {
#pragma unroll
      for (int i = 0; i < 4; i++) {
        float4 xv = *(const float4*)(xt + (c4 * 4 + i) * 64 + j0 + j4 * 4);
        acc0[j4 * 4 + 0] = fmaf(wav[i], xv.x, acc0[j4 * 4 + 0]);
        acc0[j4 * 4 + 1] = fmaf(wav[i], xv.y, acc0[j4 * 4 + 1]);
        acc0[j4 * 4 + 2] = fmaf(wav[i], xv.z, acc0[j4 * 4 + 2]);
        acc0[j4 * 4 + 3] = fmaf(wav[i], xv.w, acc0[j4 * 4 + 3]);
        acc1[j4 * 4 + 0] = fmaf(wbv[i], xv.x, acc1[j4 * 4 + 0]);
        acc1[j4 * 4 + 1] = fmaf(wbv[i], xv.y, acc1[j4 * 4 + 1]);
        acc1[j4 * 4 + 2] = fmaf(wbv[i], xv.z, acc1[j4 * 4 + 2]);
        acc1[j4 * 4 + 3] = fmaf(wbv[i], xv.w, acc1[j4 * 4 + 3]);
      }
    }
  }
  size_t row = (size_t)blk;
#pragma unroll
  for (int q = 0; q < 32; q++) {
    int j = j0 + q;
    unsigned pv = (unsigned)f2bf(acc0[q]) | ((unsigned)f2bf(acc1[q]) << 16);
    *(unsigned*)(xs + ((row * 64 + j) * 256 + c0)) = pv;                      // dir0
    *(unsigned*)(xs + (16777216u + (row * 64 + (63 - j)) * 256 + c0)) = pv;   // dir1
  }
}

// ---------------------------------------------------------------------------
// loop: persistent, fence-free. 256 blocks x 512 thr (1/CU).
// Block = slab s (64 rows) x vgroup v (32 ch); 8 waves = 2rg x 2nh x 2kh.
// Visibility rule (G16-safe): ALL h stores and tag stores are sc0sc1
// write-through (no dirty L2 lines -> no cross-XCD writeback clobber of
// partially-written lines); tag polls are sc0sc1 loads (LLC truth).
// h[t-1] staging uses default-cached global_load_lds: safe because every
// staged address is first-touch in this launch and the LLC holds the
// write-through truth; clean lines never write back. Staging is spread
// over all 8 waves (4 x 1KB windows each, pre-swizzled SOURCE, linear LDS
// dest). Single-poller wave0; one tag store per block per step. xs(t+1)
// partial is software-pipelined under the epilogue store drain.
// ---------------------------------------------------------------------------
__global__ __launch_bounds__(512, 2) void loop_kernel(
    const unsigned short* __restrict__ xs,
    const unsigned short* __restrict__ RP,
    const unsigned short* __restrict__ XP,
    const float* __restrict__ gbias2,
    unsigned short* __restrict__ hs,
    unsigned* __restrict__ tags) {
  __shared__ __align__(16) unsigned short stg[16896];   // 66 rows x 512 B
  __shared__ __align__(16) unsigned short xb[32768];    // 64 KiB xs-B frags
  __shared__ __align__(16) float redbuf[10240];         // 40 KiB, stride 20

  int bid = blockIdx.x;
  int v = bid >> 5;                              // vgroup 0..7
  int s = (bid & 7) * 4 + ((bid >> 3) & 3);      // slab 0..31 (XCD-grouped)
  int r0 = s * 64;
  int tid = threadIdx.x, lane = tid & 63, w = tid >> 6;
  int rg = w >> 2, nh = (w >> 1) & 1, kh = w & 1;
  int l15 = lane & 15, l4 = lane >> 4;
  int chb = v * 2 + nh;
  int rbase = r0 + rg * 32;

  // ---- prologue: xs-B fragments (both chb halves) -> LDS, frag-major
  for (int idx = tid; idx < 4096; idx += 512) {
    int frag = idx >> 6, ln = idx & 63;
    int c2 = frag >> 5, rem = frag & 31;
    *(s16x8*)(xb + (size_t)idx * 8) =
        *(const s16x8*)(XP + (size_t)(v * 2 + c2) * 16384 + (size_t)rem * 512 +
                        (size_t)ln * 8);
  }
  // ---- rec-B fragments -> registers (step-invariant)
  s16x8 RB[8][4];
  {
    const unsigned short* RPb = RP + (size_t)chb * 32768 + (size_t)lane * 8;
#pragma unroll
    for (int ksl = 0; ksl < 8; ksl++)
#pragma unroll
      for (int ni = 0; ni < 4; ni++)
        RB[ksl][ni] =
            *(const s16x8*)(RPb + (size_t)((kh * 8 + ksl) * 4 + ni) * 512);
  }
  float gb[4];
#pragma unroll
  for (int ni = 0; ni < 4; ni++) gb[ni] = gbias2[chb * 64 + ni * 16 + l15];
  int ch = chb * 16 + l15;
  float cst[4] = {0.f, 0.f, 0.f, 0.f};

  int Rl0 = rbase + l15, Rl1 = Rl0 + 16;
  const unsigned short* xg0 =
      xs + (size_t)(Rl0 >> 10) * 16777216u + (size_t)(Rl0 & 1023) * 16384;
  const unsigned short* xg1 =
      xs + (size_t)(Rl1 >> 10) * 16777216u + (size_t)(Rl1 & 1023) * 16384;
  int ii0 = rg * 32 + l15, ii1 = ii0 + 16;
  int tlo = rg * 32, thi = rg * 32 + 94;
  bool km1 = kh && ((s & 15) == 15) && (rg == 1) && (l15 == 15);
  bool neednb = ((s & 15) != 15);
  int pls = (lane < 8) ? s : (neednb ? (s + 1) : s);
  const unsigned* ptT = tags + pls * 16 + (lane & 7);
  bool pactive = (lane < 8) || ((lane < 16) && neednb);
  unsigned* stT = tags + s * 16 + v;
  int rsw = ((l15 + kh) & 7) << 4;
  int ar0b = (rg * 32 + l15 + kh) * 512;   // A byte base, mi0 rows
  int ar1b = ar0b + 8192;                   // +16 rows (mi1)
  // staging source per-lane offsets (shorts): group m covers rows 2m+l5 of
  // this wave's 8-row window; swizzle = XOR low-3 bits of 16B chunk by row&7
  int c5 = lane & 31, l5 = lane >> 5;
  int soff[4];
#pragma unroll
  for (int m = 0; m < 4; m++) {
    int row = 2 * m + l5;
    int csrc = (c5 & 24) | ((c5 ^ row) & 7);
    soff[m] = row * 256 + csrc * 8;
  }
  const s16x8 zz = {0, 0, 0, 0, 0, 0, 0, 0};

  __syncthreads();   // xb ready

  f32x4 accA[4], accB[4];
#pragma unroll
  for (int ni = 0; ni < 4; ni++) {
    accA[ni] = (f32x4){0.f, 0.f, 0.f, 0.f};
    accB[ni] = (f32x4){0.f, 0.f, 0.f, 0.f};
  }
  // xs partial for t=0 (prologue; later ones are pipelined at loop bottom)
  {
    int t = 0;
    if (t >= tlo && t <= thi) {
      int j0 = t - ii0, j1 = t - ii1;
      bool ib0 = ((unsigned)j0 < 64u), ib1 = ((unsigned)j1 < 64u);
      const unsigned short* px0 = xg0 + (ptrdiff_t)j0 * 256;
      const unsigned short* px1 = xg1 + (ptrdiff_t)j1 * 256;
#pragma unroll
      for (int ksl = 0; ksl < 4; ksl++) {
        int kk = (kh * 4 + ksl) * 32 + l4 * 8;
        s16x8 a0 = ib0 ? *(const s16x8*)(px0 + kk) : zz;
        s16x8 a1 = ib1 ? *(const s16x8*)(px1 + kk) : zz;
        const unsigned short* bb =
            xb + ((size_t)((nh * 8 + kh * 4 + ksl) * 4) * 64 + (size_t)lane) * 8;
#pragma unroll
        for (int ni = 0; ni < 4; ni++) {
          s16x8 b = *(const s16x8*)(bb + (size_t)ni * 512);
          accA[ni] = __builtin_amdgcn_mfma_f32_16x16x32_bf16(a0, b, accA[ni], 0, 0, 0);
          accB[ni] = __builtin_amdgcn_mfma_f32_16x16x32_bf16(a1, b, accB[ni], 0, 0, 0);
        }
      }
    }
  }

  for (int t = 0; t < 127; ++t) {
    if (t > 0) {
      // ---- single-poller: wave0 lanes 0-7 own slab, 8-15 neighbor (LLC)
      if (w == 0) {
        unsigned tgt = (unsigned)t;
        while (true) {
          unsigned tv;
          asm volatile("global_load_dword %0, %1, off sc0 sc1"
                       : "=v"(tv) : "v"(ptT));
          asm volatile("s_waitcnt vmcnt(0)" ::: "memory");
          if (__all(!pactive || (tv >= tgt))) break;
          __builtin_amdgcn_s_sleep(1);
        }
      }
      __syncthreads();
      // ---- stage h[t-1]: each wave 4 x 1KB windows (rows 8w..8w+7),
      //      wave0 also the halo row 64; default-cached global_load_lds
      const unsigned short* src =
          hs + (size_t)(t - 1) * 524288 + (size_t)r0 * 256;
      const unsigned short* pw = src + w * 2048;
      gl_lds16(pw + soff[0], stg + (w * 4 + 0) * 512);
      gl_lds16(pw + soff[1], stg + (w * 4 + 1) * 512);
      gl_lds16(pw + soff[2], stg + (w * 4 + 2) * 512);
      gl_lds16(pw + soff[3], stg + (w * 4 + 3) * 512);
      if (w == 0) gl_lds16(src + 16384 + soff[0], stg + 32 * 512);
      asm volatile("s_waitcnt vmcnt(0)" ::: "memory");
      __builtin_amdgcn_sched_barrier(0);
      __syncthreads();
      // ---- recurrent MFMAs: A from staged LDS, B from registers
      __builtin_amdgcn_s_setprio(1);
#pragma unroll
      for (int ksl = 0; ksl < 8; ksl++) {
        int cb = ((ksl * 64 + l4 * 16) ^ rsw);
        s16x8 a0 = *(const s16x8*)((const char*)stg + ar0b + cb);
        s16x8 a1 = *(const s16x8*)((const char*)stg + ar1b + cb);
        a1 = km1 ? zz : a1;
#pragma unroll
        for (int ni = 0; ni < 4; ni++) {
          accA[ni] = __builtin_amdgcn_mfma_f32_16x16x32_bf16(a0, RB[ksl][ni], accA[ni], 0, 0, 0);
          accB[ni] = __builtin_amdgcn_mfma_f32_16x16x32_bf16(a1, RB[ksl][ni], accB[ni], 0, 0, 0);
        }
      }
      __builtin_amdgcn_s_setprio(0);
    }

    // ---- K-half exchange: send partner's mi, keep own (mi = kh)
    {
      float* wsl = redbuf + (size_t)(((rg * 2 + nh) * 2 + (kh ^ 1)) * 1280);
#pragma unroll
      for (int ni = 0; ni < 4; ni++) {
        f32x4 wv = kh ? accA[ni] : accB[ni];
        *(f32x4*)(wsl + (size_t)((ni * 16 + l15) * 20 + l4 * 4)) = wv;
      }
    }
    __syncthreads();
    f32x4 ov[4];
    {
      const float* rsl = redbuf + (size_t)(((rg * 2 + nh) * 2 + kh) * 1280);
#pragma unroll
      for (int ni = 0; ni < 4; ni++) {
        f32x4 p = *(const f32x4*)(rsl + (size_t)((ni * 16 + l15) * 20 + l4 * 4));
        ov[ni] = (kh ? accB[ni] : accA[ni]) + p;
      }
    }
    // ---- fused LSTM epilogue on own 16 rows (mi = kh); sc0sc1 stores only
    unsigned short* hout = hs + (size_t)t * 524288;
#pragma unroll
    for (int r = 0; r < 4; r++) {
      int R = rbase + kh * 16 + l4 * 4 + r;
      float xi = ov[0][r] + gb[0];
      float xf = ov[1][r] + gb[1];
      float xg_ = ov[2][r] + gb[2];
      float xo = ov[3][r] + gb[3];
      float si = 1.f / (1.f + __expf(-xi));
      float sf = 1.f / (1.f + __expf(-xf));
      float so = 1.f / (1.f + __expf(-xo));
      float tg = 1.f - 2.f / (__expf(2.f * xg_) + 1.f);
      float cn = sf * cst[r] + si * tg;
      cst[r] = cn;
      float th = 1.f - 2.f / (__expf(2.f * cn) + 1.f);
      unsigned short hv = f2bf(so * th);
      const unsigned short* pst = hout + (size_t)R * 256 + ch;
      asm volatile("global_store_short %0, %1, off sc0 sc1"
                   :: "v"(pst), "v"(hv));
    }
    // ---- pipelined xs partial for t+1 (overlaps the store drain)
#pragma unroll
    for (int ni = 0; ni < 4; ni++) {
      accA[ni] = (f32x4){0.f, 0.f, 0.f, 0.f};
      accB[ni] = (f32x4){0.f, 0.f, 0.f, 0.f};
    }
    if (t < 126) {
      int tn = t + 1;
      if (tn >= tlo && tn <= thi) {
        int j0 = tn - ii0, j1 = tn - ii1;
        bool ib0 = ((unsigned)j0 < 64u), ib1 = ((unsigned)j1 < 64u);
        const unsigned short* px0 = xg0 + (ptrdiff_t)j0 * 256;
        const unsigned short* px1 = xg1 + (ptrdiff_t)j1 * 256;
#pragma unroll
        for (int ksl = 0; ksl < 4; ksl++) {
          int kk = (kh * 4 + ksl) * 32 + l4 * 8;
          s16x8 a0 = ib0 ? *(const s16x8*)(px0 + kk) : zz;
          s16x8 a1 = ib1 ? *(const s16x8*)(px1 + kk) : zz;
          const unsigned short* bb =
              xb + ((size_t)((nh * 8 + kh * 4 + ksl) * 4) * 64 + (size_t)lane) * 8;
#pragma unroll
          for (int ni = 0; ni < 4; ni++) {
            s16x8 b = *(const s16x8*)(bb + (size_t)ni * 512);
            accA[ni] = __builtin_amdgcn_mfma_f32_16x16x32_bf16(a0, b, accA[ni], 0, 0, 0);
            accB[ni] = __builtin_amdgcn_mfma_f32_16x16x32_bf16(a1, b, accB[ni], 0, 0, 0);
          }
        }
      }
    }
    // ---- drain + bottom barrier + single tag publish (sc0sc1, monotone)
    asm volatile("s_waitcnt vmcnt(0)" ::: "memory");
    __syncthreads();
    if (tid == 0 && t < 126) {
      unsigned tv = (unsigned)(t + 1);
      asm volatile("global_store_dword %0, %1, off sc0 sc1"
                   :: "v"(stT), "v"(tv));
    }
  }
}

// ---------------------------------------------------------------------------
// gather: out[b,o,hh,j] = hs0[hh+j][row][c0+hh] + (hh>0)*hs1[hh-1+63-j][row][c0+hh-1]
// ---------------------------------------------------------------------------
__global__ __launch_bounds__(256) void gather_kernel(
    const unsigned short* __restrict__ hs, float* __restrict__ out) {
  __shared__ unsigned short slab0[127 * 66 + 2];
  __shared__ unsigned short slab1[127 * 66 + 2];
  int blk = blockIdx.x;                    // bb*256 + o
  int bb = blk >> 8, o = blk & 255;
  int row = bb * 64 + (o >> 2);
  int c0 = (o & 3) * 64;
  int tid = threadIdx.x;
  for (int idx = tid; idx < 127 * 32; idx += 256) {
    int tt = idx >> 5, cu = idx & 31;
    unsigned v0 = *(const unsigned*)(hs + ((size_t)tt * RT_ + row) * 256 + c0 + cu * 2);
    unsigned v1 = *(const unsigned*)(hs + ((size_t)tt * RT_ + 1024 + row) * 256 + c0 + cu * 2);
    *(unsigned*)(slab0 + tt * 66 + cu * 2) = v0;
    *(unsigned*)(slab1 + tt * 66 + cu * 2) = v1;
  }
  __syncthreads();
  int j = tid & 63;
  int hh0 = (tid >> 6) * 16;
  float* ob = out + (size_t)blk * 4096;
  for (int hh = hh0; hh < hh0 + 16; hh++) {
    float v = bf2f(slab0[(hh + j) * 66 + hh]);
    if (hh > 0) v += bf2f(slab1[(hh - 1 + 63 - j) * 66 + (hh - 1)]);
    ob[hh * 64 + j] = v;
  }
}

// ---------------------------------------------------------------------------
extern "C" void kernel_launch(void* const* d_in, const int* in_sizes, int n_in,
                              void* d_out, int out_size, void* d_ws, size_t ws_size,
                              hipStream_t stream) {
  const float* x     = (const float*)d_in[0];
  const float* w_i2s = (const float*)d_in[1];
  const float* b_i2s = (const float*)d_in[2];
  const float* w_ih  = (const float*)d_in[3];
  const float* b_ih  = (const float*)d_in[4];
  const float* b_hh  = (const float*)d_in[5];
  const float* k0    = (const float*)d_in[6];
  const float* k1    = (const float*)d_in[7];
  const float* b_s2s = (const float*)d_in[8];
  float* out = (float*)d_out;

  char* ws = (char*)d_ws;
  // workspace map (bytes)
  float*          wm     = (float*)(ws + 0);                 //   256 KiB
  float*          cvec   = (float*)(ws + 262144);            //     1 KiB
  float*          gbias  = (float*)(ws + 263168);            //     4 KiB
  float*          gbias2 = (float*)(ws + 267264);            //     4 KiB
  unsigned*       tags   = (unsigned*)(ws + 271360);         //     2 KiB (16K rsvd)
  unsigned short* XP     = (unsigned short*)(ws + 287744);   //   512 KiB
  unsigned short* RP     = (unsigned short*)(ws + 812032);   //     1 MiB
  unsigned short* xs     = (unsigned short*)(ws + 1860608);  //    64 MiB
  unsigned short* hs     = (unsigned short*)(ws + 68969472); //   127 MiB
  const size_t NEEDED = 202138624;
  if (ws_size < NEEDED) return;  // workspace too small; fail loudly via mismatch

  prep_kernel<<<1286, 256, 0, stream>>>(w_i2s, b_i2s, w_ih, b_ih, b_hh, b_s2s,
                                        wm, XP, cvec, gbias, tags);
  prep2_kernel<<<256, 256, 0, stream>>>(w_ih, k0, k1, cvec, gbias, RP, gbias2);
  xs_kernel<<<1024, 256, 65536, stream>>>(x, wm, xs);

  {
    const unsigned short* a0 = xs;
    const unsigned short* a1 = RP;
    const unsigned short* a2 = XP;
    const float*          a3 = gbias2;
    unsigned short*       a4 = hs;
    unsigned*             a5 = tags;
    void* kargs[6] = {(void*)&a0, (void*)&a1, (void*)&a2,
                      (void*)&a3, (void*)&a4, (void*)&a5};
    hipLaunchCooperativeKernel((const void*)loop_kernel, dim3(NBLK), dim3(512),
                               kargs, 0, stream);
  }

  gather_kernel<<<4096, 256, 0, stream>>>(hs, out);
}